// Round 2
// baseline (198.369 us; speedup 1.0000x reference)
//
#include <hip/hip_runtime.h>
#include <utility>
#include <type_traits>

#define FEPS 1e-8f

// ---- compile-time for: generates straight-line code with literal indices so
// early SROA scalarizes the local arrays into registers (the round-1 kernel
// left them in scratch: VGPR_Count=48 with >72 live floats). ----
template<class F, int... Is>
__device__ __forceinline__ void sf_impl(F&& f, std::integer_sequence<int, Is...>) {
    (f(std::integral_constant<int, Is>{}), ...);
}
template<int N, class F>
__device__ __forceinline__ void static_for(F&& f) {
    sf_impl((F&&)f, std::make_integer_sequence<int, N>{});
}

// Order-isomorphic to atan2(y, x) (monotone in angle, same +/-pi cut).
__device__ __forceinline__ float pseudo_angle(float x, float y) {
    float d = fabsf(x) + fabsf(y);
    float q = x / fmaxf(d, 1e-38f);
    return copysignf(1.0f - q, y);
}

__global__ __launch_bounds__(256, 2) void riou_kernel(
    const float* __restrict__ pred, const float* __restrict__ target,
    const int* __restrict__ pos_idx, float* __restrict__ out,
    double* __restrict__ ws_num, int* __restrict__ ws_den,
    unsigned* __restrict__ ws_ticket, int n)
{
    int gid = blockIdx.x * blockDim.x + threadIdx.x;
    float lnum = 0.0f;
    int   lden = 0;

    if (gid < n) {
        const float DEG = 0.017453292519943295f;
        float p0 = pred[gid*5+0], p1 = pred[gid*5+1], p2 = pred[gid*5+2],
              p3 = pred[gid*5+3], p4 = pred[gid*5+4];
        float t0 = target[gid*5+0], t1 = target[gid*5+1], t2 = target[gid*5+2],
              t3 = target[gid*5+3], t4 = target[gid*5+4];

        float a1 = p4 * DEG;                       // deg2rad(pred angle)
        float a2 = (t4 * 180.0f - 180.0f) * DEG;   // deg2rad(target*180-180)

        float s1, c1_; sincosf(a1, &s1, &c1_);
        float s2, c2_; sincosf(a2, &s2, &c2_);

        float c1x[4], c1y[4], c2x[4], c2y[4];
        static_for<4>([&](auto K) {
            constexpr int k = decltype(K)::value;
            constexpr float SX[4] = {0.5f, -0.5f, -0.5f, 0.5f};
            constexpr float SY[4] = {0.5f, 0.5f, -0.5f, -0.5f};
            float xs = SX[k] * p2, ys = SY[k] * p3;
            c1x[k] = xs * c1_ - ys * s1 + p0;
            c1y[k] = xs * s1 + ys * c1_ + p1;
            float xs2 = SX[k] * t2, ys2 = SY[k] * t3;
            c2x[k] = xs2 * c2_ - ys2 * s2 + t0;
            c2y[k] = xs2 * s2 + ys2 * c2_ + t1;
        });

        float vx[24], vy[24], ang[24];
        unsigned vmask = 0;   // bit i = vertex i valid

        // --- box_in_box: c1 corners in box2 -> bits 0..3
        {
            float ax = c2x[0], ay = c2y[0];
            float abx = c2x[1] - ax, aby = c2y[1] - ay;
            float adx = c2x[3] - ax, ady = c2y[3] - ay;
            float iab = 1.0f / (abx*abx + aby*aby + FEPS);
            float iad = 1.0f / (adx*adx + ady*ady + FEPS);
            static_for<4>([&](auto K) {
                constexpr int k = decltype(K)::value;
                float amx = c1x[k] - ax, amy = c1y[k] - ay;
                float pab  = (abx*amx + aby*amy) * iab;
                float pad_ = (adx*amx + ady*amy) * iad;
                bool v = (pab > -1e-6f) && (pab < 1.0f + 1e-6f) &&
                         (pad_ > -1e-6f) && (pad_ < 1.0f + 1e-6f);
                vmask |= (v ? 1u : 0u) << k;
                vx[k] = c1x[k]; vy[k] = c1y[k];
            });
        }
        // --- box_in_box: c2 corners in box1 -> bits 4..7
        {
            float ax = c1x[0], ay = c1y[0];
            float abx = c1x[1] - ax, aby = c1y[1] - ay;
            float adx = c1x[3] - ax, ady = c1y[3] - ay;
            float iab = 1.0f / (abx*abx + aby*aby + FEPS);
            float iad = 1.0f / (adx*adx + ady*ady + FEPS);
            static_for<4>([&](auto K) {
                constexpr int k = decltype(K)::value;
                float amx = c2x[k] - ax, amy = c2y[k] - ay;
                float pab  = (abx*amx + aby*amy) * iab;
                float pad_ = (adx*amx + ady*amy) * iad;
                bool v = (pab > -1e-6f) && (pab < 1.0f + 1e-6f) &&
                         (pad_ > -1e-6f) && (pad_ < 1.0f + 1e-6f);
                vmask |= (v ? 1u : 0u) << (4 + k);
                vx[4+k] = c2x[k]; vy[4+k] = c2y[k];
            });
        }
        // --- edge intersections -> bits 8..23
        static_for<4>([&](auto I) {
            constexpr int i = decltype(I)::value;
            float px = c1x[i], py = c1y[i];
            float rx = c1x[(i+1)&3] - px, ry = c1y[(i+1)&3] - py;
            static_for<4>([&](auto J) {
                constexpr int j = decltype(J)::value;
                float qx = c2x[j], qy = c2y[j];
                float sx = c2x[(j+1)&3] - qx, sy = c2y[(j+1)&3] - qy;
                float rxs = rx*sy - ry*sx;
                float qpx = qx - px, qpy = qy - py;
                float inv = 1.0f / (rxs + FEPS);
                float tt = (qpx*sy - qpy*sx) * inv;
                float uu = (qpx*ry - qpy*rx) * inv;
                bool mk = (tt > 0.0f) && (tt < 1.0f) && (uu > 0.0f) && (uu < 1.0f);
                constexpr int idx = 8 + i*4 + j;
                vmask |= (mk ? 1u : 0u) << idx;
                vx[idx] = mk ? (px + tt*rx) : 0.0f;
                vy[idx] = mk ? (py + tt*ry) : 0.0f;
            });
        });

        // --- convex_area: mean of valid vertices
        float sumx = 0.0f, sumy = 0.0f;
        static_for<24>([&](auto I) {
            constexpr int i = decltype(I)::value;
            bool v = (vmask >> i) & 1u;
            sumx += v ? vx[i] : 0.0f;
            sumy += v ? vy[i] : 0.0f;
        });
        int nv = __popc(vmask);
        float invn = 1.0f / fmaxf((float)nv, 1.0f);
        float mx = sumx * invn, my = sumy * invn;

        static_for<24>([&](auto I) {
            constexpr int i = decltype(I)::value;
            float dx = vx[i] - mx, dy = vy[i] - my;
            vx[i] = dx; vy[i] = dy;
            bool v = (vmask >> i) & 1u;
            ang[i] = v ? pseudo_angle(dx, dy) : 1e9f;
        });

        // --- odd-even transposition sort, 24 phases, straight-line
        static_for<24>([&](auto PH) {
            constexpr int ph = decltype(PH)::value;
            static_for<12>([&](auto K) {
                constexpr int i = (ph & 1) + 2 * decltype(K)::value;
                if constexpr (i + 1 < 24) {
                    float a0 = ang[i], a1v = ang[i+1];
                    bool sw = a1v < a0;
                    ang[i]   = sw ? a1v : a0;
                    ang[i+1] = sw ? a0  : a1v;
                    float x0 = vx[i], x1 = vx[i+1];
                    vx[i]   = sw ? x1 : x0;
                    vx[i+1] = sw ? x0 : x1;
                    float y0 = vy[i], y1 = vy[i+1];
                    vy[i]   = sw ? y1 : y0;
                    vy[i+1] = sw ? y0 : y1;
                }
            });
        });

        // --- shoelace; invalid slots (ang==1e9) -> first sorted vertex
        float v0x = vx[0], v0y = vy[0];
        float cs = 0.0f;
        static_for<24>([&](auto I) {
            constexpr int i = decltype(I)::value;
            constexpr int j = (i + 1) % 24;
            float xi = (ang[i] < 1e8f) ? vx[i] : v0x;
            float yi = (ang[i] < 1e8f) ? vy[i] : v0y;
            float xj = (ang[j] < 1e8f) ? vx[j] : v0x;
            float yj = (ang[j] < 1e8f) ? vy[j] : v0y;
            cs += xi * yj - yi * xj;
        });
        float inter = (nv >= 3) ? (0.5f * fabsf(cs)) : 0.0f;

        float area1 = p2 * p3;
        float area2 = t2 * t3;
        float uni = area1 + area2 - inter;
        float iou = inter / (uni + FEPS);
        iou = fminf(fmaxf(iou, 1e-7f), 1.0f - 1e-7f);

        out[1 + gid] = iou;

        int m = (pos_idx[gid] != 0) ? 1 : 0;
        lnum = (1.0f - iou) * (float)m;
        lden = m;
    }

    // --- block reduction for the loss
    #pragma unroll
    for (int off = 32; off > 0; off >>= 1) {
        lnum += __shfl_down(lnum, off);
        lden += __shfl_down(lden, off);
    }
    __shared__ float snum[4];
    __shared__ int   sden[4];
    int wave = threadIdx.x >> 6, lane = threadIdx.x & 63;
    if (lane == 0) { snum[wave] = lnum; sden[wave] = lden; }
    __syncthreads();
    if (threadIdx.x == 0) {
        float bn = snum[0] + snum[1] + snum[2] + snum[3];
        int   bd = sden[0] + sden[1] + sden[2] + sden[3];
        atomicAdd(ws_num, (double)bn);
        atomicAdd(ws_den, bd);
        __threadfence();
        unsigned t = atomicAdd(ws_ticket, 1u);
        if (t == gridDim.x - 1) {          // last block finalizes the loss
            __threadfence();
            double num = atomicAdd(ws_num, 0.0);   // atomic 64b read (no tearing)
            int    den = atomicAdd(ws_den, 0);
            out[0] = (float)(num / (double)max(den, 1));
        }
    }
}

extern "C" void kernel_launch(void* const* d_in, const int* in_sizes, int n_in,
                              void* d_out, int out_size, void* d_ws, size_t ws_size,
                              hipStream_t stream) {
    const float* pred   = (const float*)d_in[0];
    const float* target = (const float*)d_in[1];
    const int*   posidx = (const int*)d_in[2];
    float* out = (float*)d_out;

    int n = in_sizes[0] / 5;

    double*   ws_num    = (double*)d_ws;
    int*      ws_den    = (int*)((char*)d_ws + 8);
    unsigned* ws_ticket = (unsigned*)((char*)d_ws + 12);
    hipMemsetAsync(d_ws, 0, 16, stream);

    int block = 256;
    int grid = (n + block - 1) / block;
    riou_kernel<<<grid, block, 0, stream>>>(pred, target, posidx, out,
                                            ws_num, ws_den, ws_ticket, n);
}

// Round 3
// 189.070 us; speedup vs baseline: 1.0492x; 1.0492x over previous
//
#include <hip/hip_runtime.h>

#define FEPS 1e-8f

// Liang-Barsky clip of segment p + t*d, t in [0,1], against the rectangle
// {center c, unit axes u and v=perp(u), half-sizes hw,hh}; accumulates the
// shoelace contribution cross(P(t0), P(t1)) of the surviving sub-segment.
// Boundary of P∩Q = (edges of P inside Q) ∪ (edges of Q inside P), each in
// original CCW order; shoelace over directed pieces is ordering-invariant.
__device__ __forceinline__ void clip_edge_accum(
    float px, float py, float dx, float dy,
    float cx, float cy, float ux, float uy,
    float hw, float hh, float& sum)
{
    float rx = px - cx, ry = py - cy;
    // axis u
    float a0 = rx * ux + ry * uy;
    float b0 = dx * ux + dy * uy;
    // axis v = (-uy, ux)
    float a1 = -rx * uy + ry * ux;
    float b1 = -dx * uy + dy * ux;

    float t0 = 0.0f, t1 = 1.0f;
    bool reject = false;

    {   // slab |a0 + t*b0| <= hw
        bool par = fabsf(b0) < 1e-12f;
        float inv = 1.0f / (par ? 1.0f : b0);
        float tA = (hw - a0) * inv, tB = (-hw - a0) * inv;
        float lo = fminf(tA, tB), hi = fmaxf(tA, tB);
        t0 = par ? t0 : fmaxf(t0, lo);
        t1 = par ? t1 : fminf(t1, hi);
        reject = reject || (par && (fabsf(a0) > hw));
    }
    {   // slab |a1 + t*b1| <= hh
        bool par = fabsf(b1) < 1e-12f;
        float inv = 1.0f / (par ? 1.0f : b1);
        float tA = (hh - a1) * inv, tB = (-hh - a1) * inv;
        float lo = fminf(tA, tB), hi = fmaxf(tA, tB);
        t0 = par ? t0 : fmaxf(t0, lo);
        t1 = par ? t1 : fminf(t1, hi);
        reject = reject || (par && (fabsf(a1) > hh));
    }

    bool ok = (!reject) && (t1 > t0);
    float sx = px + t0 * dx, sy = py + t0 * dy;
    float ex = px + t1 * dx, ey = py + t1 * dy;
    float cr = sx * ey - ex * sy;
    sum += ok ? cr : 0.0f;
}

__global__ __launch_bounds__(256, 2) void riou_kernel(
    const float* __restrict__ pred, const float* __restrict__ target,
    const int* __restrict__ pos_idx, float* __restrict__ out,
    double* __restrict__ ws_num, int* __restrict__ ws_den,
    unsigned* __restrict__ ws_ticket, int n)
{
    int gid = blockIdx.x * blockDim.x + threadIdx.x;
    float lnum = 0.0f;
    int   lden = 0;

    if (gid < n) {
        const float DEG = 0.017453292519943295f;
        float p0 = pred[gid*5+0], p1 = pred[gid*5+1], p2 = pred[gid*5+2],
              p3 = pred[gid*5+3], p4 = pred[gid*5+4];
        float t0 = target[gid*5+0], t1 = target[gid*5+1], t2 = target[gid*5+2],
              t3 = target[gid*5+3], t4 = target[gid*5+4];

        float a1 = p4 * DEG;                       // deg2rad(pred angle)
        float a2 = (t4 * 180.0f - 180.0f) * DEG;   // deg2rad(target*180-180)

        float s1, c1_; sincosf(a1, &s1, &c1_);
        float s2, c2_; sincosf(a2, &s2, &c2_);

        float hw1 = 0.5f * p2, hh1 = 0.5f * p3;
        float hw2 = 0.5f * t2, hh2 = 0.5f * t3;

        // CCW corners (matches reference order: (+,+), (-,+), (-,-), (+,-))
        const float SX[4] = {0.5f, -0.5f, -0.5f, 0.5f};
        const float SY[4] = {0.5f, 0.5f, -0.5f, -0.5f};
        float P1x[4], P1y[4], P2x[4], P2y[4];
        #pragma unroll
        for (int k = 0; k < 4; ++k) {
            float xs = SX[k] * p2, ys = SY[k] * p3;
            P1x[k] = xs * c1_ - ys * s1 + p0;
            P1y[k] = xs * s1 + ys * c1_ + p1;
            float xs2 = SX[k] * t2, ys2 = SY[k] * t3;
            P2x[k] = xs2 * c2_ - ys2 * s2 + t0;
            P2y[k] = xs2 * s2 + ys2 * c2_ + t1;
        }

        float sum = 0.0f;
        // edges of box1 clipped against box2
        #pragma unroll
        for (int k = 0; k < 4; ++k) {
            int kn = (k + 1) & 3;
            clip_edge_accum(P1x[k], P1y[k], P1x[kn] - P1x[k], P1y[kn] - P1y[k],
                            t0, t1, c2_, s2, hw2, hh2, sum);
        }
        // edges of box2 clipped against box1
        #pragma unroll
        for (int k = 0; k < 4; ++k) {
            int kn = (k + 1) & 3;
            clip_edge_accum(P2x[k], P2y[k], P2x[kn] - P2x[k], P2y[kn] - P2y[k],
                            p0, p1, c1_, s1, hw1, hh1, sum);
        }

        float inter = 0.5f * fabsf(sum);
        float area1 = p2 * p3;
        float area2 = t2 * t3;
        float uni = area1 + area2 - inter;
        float iou = inter / (uni + FEPS);
        iou = fminf(fmaxf(iou, 1e-7f), 1.0f - 1e-7f);

        out[1 + gid] = iou;

        int m = (pos_idx[gid] != 0) ? 1 : 0;
        lnum = (1.0f - iou) * (float)m;
        lden = m;
    }

    // --- block reduction for the loss
    #pragma unroll
    for (int off = 32; off > 0; off >>= 1) {
        lnum += __shfl_down(lnum, off);
        lden += __shfl_down(lden, off);
    }
    __shared__ float snum[4];
    __shared__ int   sden[4];
    int wave = threadIdx.x >> 6, lane = threadIdx.x & 63;
    if (lane == 0) { snum[wave] = lnum; sden[wave] = lden; }
    __syncthreads();
    if (threadIdx.x == 0) {
        float bn = snum[0] + snum[1] + snum[2] + snum[3];
        int   bd = sden[0] + sden[1] + sden[2] + sden[3];
        atomicAdd(ws_num, (double)bn);
        atomicAdd(ws_den, bd);
        __threadfence();
        unsigned t = atomicAdd(ws_ticket, 1u);
        if (t == gridDim.x - 1) {          // last block finalizes the loss
            __threadfence();
            double num = atomicAdd(ws_num, 0.0);   // atomic 64b read
            int    den = atomicAdd(ws_den, 0);
            out[0] = (float)(num / (double)max(den, 1));
        }
    }
}

extern "C" void kernel_launch(void* const* d_in, const int* in_sizes, int n_in,
                              void* d_out, int out_size, void* d_ws, size_t ws_size,
                              hipStream_t stream) {
    const float* pred   = (const float*)d_in[0];
    const float* target = (const float*)d_in[1];
    const int*   posidx = (const int*)d_in[2];
    float* out = (float*)d_out;

    int n = in_sizes[0] / 5;

    double*   ws_num    = (double*)d_ws;
    int*      ws_den    = (int*)((char*)d_ws + 8);
    unsigned* ws_ticket = (unsigned*)((char*)d_ws + 12);
    hipMemsetAsync(d_ws, 0, 16, stream);

    int block = 256;
    int grid = (n + block - 1) / block;
    riou_kernel<<<grid, block, 0, stream>>>(pred, target, posidx, out,
                                            ws_num, ws_den, ws_ticket, n);
}

// Round 4
// 94.253 us; speedup vs baseline: 2.1046x; 2.0060x over previous
//
#include <hip/hip_runtime.h>

#define FEPS 1e-8f
#define ELEMS 4
#define NSLOTS 32

// Liang-Barsky clip of segment p + t*d, t in [0,1], against rectangle
// {center c, unit axis (ux,uy), half-sizes hw,hh}; accumulates shoelace
// contribution cross(P(t0), P(t1)) of the surviving sub-segment.
// Boundary of P∩Q = (edges of P in Q) ∪ (edges of Q in P) in CCW order;
// the shoelace sum over directed pieces is ordering-invariant.
__device__ __forceinline__ void clip_edge_accum(
    float px, float py, float dx, float dy,
    float cx, float cy, float ux, float uy,
    float hw, float hh, float& sum)
{
    float rx = px - cx, ry = py - cy;
    float a0 = rx * ux + ry * uy;
    float b0 = dx * ux + dy * uy;
    float a1 = -rx * uy + ry * ux;
    float b1 = -dx * uy + dy * ux;

    float t0 = 0.0f, t1 = 1.0f;
    bool reject = false;
    {
        bool par = fabsf(b0) < 1e-12f;
        float inv = 1.0f / (par ? 1.0f : b0);
        float tA = (hw - a0) * inv, tB = (-hw - a0) * inv;
        t0 = par ? t0 : fmaxf(t0, fminf(tA, tB));
        t1 = par ? t1 : fminf(t1, fmaxf(tA, tB));
        reject = reject || (par && (fabsf(a0) > hw));
    }
    {
        bool par = fabsf(b1) < 1e-12f;
        float inv = 1.0f / (par ? 1.0f : b1);
        float tA = (hh - a1) * inv, tB = (-hh - a1) * inv;
        t0 = par ? t0 : fmaxf(t0, fminf(tA, tB));
        t1 = par ? t1 : fminf(t1, fmaxf(tA, tB));
        reject = reject || (par && (fabsf(a1) > hh));
    }
    bool ok = (!reject) && (t1 > t0);
    float sx = px + t0 * dx, sy = py + t0 * dy;
    float ex = px + t1 * dx, ey = py + t1 * dy;
    sum += ok ? (sx * ey - ex * sy) : 0.0f;
}

__device__ __forceinline__ float one_iou(
    float p0, float p1, float p2, float p3, float p4,
    float t0, float t1, float t2, float t3, float t4)
{
    const float DEG = 0.017453292519943295f;
    float a1 = p4 * DEG;                       // deg2rad(pred angle)
    float a2 = (t4 * 180.0f - 180.0f) * DEG;   // deg2rad(target*180-180)
    float s1, c1_; sincosf(a1, &s1, &c1_);
    float s2, c2_; sincosf(a2, &s2, &c2_);

    float hw1 = 0.5f * p2, hh1 = 0.5f * p3;
    float hw2 = 0.5f * t2, hh2 = 0.5f * t3;

    const float SX[4] = {0.5f, -0.5f, -0.5f, 0.5f};
    const float SY[4] = {0.5f, 0.5f, -0.5f, -0.5f};
    float P1x[4], P1y[4], P2x[4], P2y[4];
    #pragma unroll
    for (int k = 0; k < 4; ++k) {
        float xs = SX[k] * p2, ys = SY[k] * p3;
        P1x[k] = xs * c1_ - ys * s1 + p0;
        P1y[k] = xs * s1 + ys * c1_ + p1;
        float xs2 = SX[k] * t2, ys2 = SY[k] * t3;
        P2x[k] = xs2 * c2_ - ys2 * s2 + t0;
        P2y[k] = xs2 * s2 + ys2 * c2_ + t1;
    }

    float sum = 0.0f;
    #pragma unroll
    for (int k = 0; k < 4; ++k) {
        int kn = (k + 1) & 3;
        clip_edge_accum(P1x[k], P1y[k], P1x[kn]-P1x[k], P1y[kn]-P1y[k],
                        t0, t1, c2_, s2, hw2, hh2, sum);
    }
    #pragma unroll
    for (int k = 0; k < 4; ++k) {
        int kn = (k + 1) & 3;
        clip_edge_accum(P2x[k], P2y[k], P2x[kn]-P2x[k], P2y[kn]-P2y[k],
                        p0, p1, c1_, s1, hw1, hh1, sum);
    }

    float inter = 0.5f * fabsf(sum);
    float uni = p2 * p3 + t2 * t3 - inter;
    float iou = inter / (uni + FEPS);
    return fminf(fmaxf(iou, 1e-7f), 1.0f - 1e-7f);
}

// ws layout: NSLOTS slots of 64B each: {double num; int den; pad}
__global__ __launch_bounds__(256) void riou_kernel(
    const float* __restrict__ pred, const float* __restrict__ target,
    const int* __restrict__ pos_idx, float* __restrict__ out,
    char* __restrict__ ws, int n)
{
    int tid = blockIdx.x * blockDim.x + threadIdx.x;
    int base = tid * ELEMS;
    float lnum = 0.0f;
    int   lden = 0;

    if (base + ELEMS <= n) {
        // 80 contiguous bytes per thread, 16B-aligned (base % 4 == 0)
        union { float4 q[5]; float f[20]; } P, T;
        const float4* pp = (const float4*)(pred + (size_t)base * 5);
        const float4* tp = (const float4*)(target + (size_t)base * 5);
        #pragma unroll
        for (int k = 0; k < 5; ++k) { P.q[k] = pp[k]; T.q[k] = tp[k]; }
        union { int4 q; int i[4]; } M;
        M.q = *(const int4*)(pos_idx + base);

        #pragma unroll
        for (int e = 0; e < ELEMS; ++e) {
            float iou = one_iou(P.f[e*5+0], P.f[e*5+1], P.f[e*5+2],
                                P.f[e*5+3], P.f[e*5+4],
                                T.f[e*5+0], T.f[e*5+1], T.f[e*5+2],
                                T.f[e*5+3], T.f[e*5+4]);
            out[1 + base + e] = iou;
            int m = (M.i[e] != 0) ? 1 : 0;
            lnum += (1.0f - iou) * (float)m;
            lden += m;
        }
    } else {
        for (int e = 0; e < ELEMS; ++e) {
            int g = base + e;
            if (g < n) {
                float iou = one_iou(pred[g*5+0], pred[g*5+1], pred[g*5+2],
                                    pred[g*5+3], pred[g*5+4],
                                    target[g*5+0], target[g*5+1], target[g*5+2],
                                    target[g*5+3], target[g*5+4]);
                out[1 + g] = iou;
                int m = (pos_idx[g] != 0) ? 1 : 0;
                lnum += (1.0f - iou) * (float)m;
                lden += m;
            }
        }
    }

    // block reduction
    #pragma unroll
    for (int off = 32; off > 0; off >>= 1) {
        lnum += __shfl_down(lnum, off);
        lden += __shfl_down(lden, off);
    }
    __shared__ float snum[4];
    __shared__ int   sden[4];
    int wave = threadIdx.x >> 6, lane = threadIdx.x & 63;
    if (lane == 0) { snum[wave] = lnum; sden[wave] = lden; }
    __syncthreads();
    if (threadIdx.x == 0) {
        float bn = snum[0] + snum[1] + snum[2] + snum[3];
        int   bd = sden[0] + sden[1] + sden[2] + sden[3];
        char* slot = ws + (size_t)(blockIdx.x & (NSLOTS - 1)) * 64;
        atomicAdd((double*)slot, (double)bn);
        atomicAdd((int*)(slot + 8), bd);
    }
}

__global__ void riou_finalize(const char* __restrict__ ws,
                              float* __restrict__ out)
{
    int lane = threadIdx.x;
    double num = 0.0; int den = 0;
    if (lane < NSLOTS) {
        const char* slot = ws + (size_t)lane * 64;
        num = *(const double*)slot;
        den = *(const int*)(slot + 8);
    }
    #pragma unroll
    for (int off = 32; off > 0; off >>= 1) {
        num += __shfl_down(num, off);
        den += __shfl_down(den, off);
    }
    if (lane == 0) out[0] = (float)(num / (double)max(den, 1));
}

extern "C" void kernel_launch(void* const* d_in, const int* in_sizes, int n_in,
                              void* d_out, int out_size, void* d_ws, size_t ws_size,
                              hipStream_t stream) {
    const float* pred   = (const float*)d_in[0];
    const float* target = (const float*)d_in[1];
    const int*   posidx = (const int*)d_in[2];
    float* out = (float*)d_out;

    int n = in_sizes[0] / 5;

    hipMemsetAsync(d_ws, 0, NSLOTS * 64, stream);

    int block = 256;
    int grid = (n + block * ELEMS - 1) / (block * ELEMS);
    riou_kernel<<<grid, block, 0, stream>>>(pred, target, posidx, out,
                                            (char*)d_ws, n);
    riou_finalize<<<1, 64, 0, stream>>>((const char*)d_ws, out);
}

// Round 5
// 94.161 us; speedup vs baseline: 2.1067x; 1.0010x over previous
//
#include <hip/hip_runtime.h>

#define FEPS 1e-8f

// Liang-Barsky clip of segment p + t*d, t in [0,1], against rectangle
// {center c, unit axis (ux,uy), half-sizes hw,hh}; accumulates shoelace
// contribution cross(P(t0), P(t1)) of the surviving sub-segment.
// Boundary of P∩Q = (edges of P in Q) ∪ (edges of Q in P) in CCW order;
// the shoelace sum over directed pieces is ordering-invariant.
__device__ __forceinline__ void clip_edge_accum(
    float px, float py, float dx, float dy,
    float cx, float cy, float ux, float uy,
    float hw, float hh, float& sum)
{
    float rx = px - cx, ry = py - cy;
    float a0 = rx * ux + ry * uy;
    float b0 = dx * ux + dy * uy;
    float a1 = -rx * uy + ry * ux;
    float b1 = -dx * uy + dy * ux;

    float t0 = 0.0f, t1 = 1.0f;
    bool reject = false;
    {
        bool par = fabsf(b0) < 1e-12f;
        float inv = 1.0f / (par ? 1.0f : b0);
        float tA = (hw - a0) * inv, tB = (-hw - a0) * inv;
        t0 = par ? t0 : fmaxf(t0, fminf(tA, tB));
        t1 = par ? t1 : fminf(t1, fmaxf(tA, tB));
        reject = reject || (par && (fabsf(a0) > hw));
    }
    {
        bool par = fabsf(b1) < 1e-12f;
        float inv = 1.0f / (par ? 1.0f : b1);
        float tA = (hh - a1) * inv, tB = (-hh - a1) * inv;
        t0 = par ? t0 : fmaxf(t0, fminf(tA, tB));
        t1 = par ? t1 : fminf(t1, fmaxf(tA, tB));
        reject = reject || (par && (fabsf(a1) > hh));
    }
    bool ok = (!reject) && (t1 > t0);
    float sx = px + t0 * dx, sy = py + t0 * dy;
    float ex = px + t1 * dx, ey = py + t1 * dy;
    sum += ok ? (sx * ey - ex * sy) : 0.0f;
}

__device__ __forceinline__ float one_iou(
    float p0, float p1, float p2, float p3, float p4,
    float t0, float t1, float t2, float t3, float t4)
{
    const float DEG = 0.017453292519943295f;
    float a1 = p4 * DEG;                       // deg2rad(pred angle)
    float a2 = (t4 * 180.0f - 180.0f) * DEG;   // deg2rad(target*180-180)
    // native v_sin/v_cos (plenty accurate at the 1.875e-2 threshold)
    float s1 = __sinf(a1), c1_ = __cosf(a1);
    float s2 = __sinf(a2), c2_ = __cosf(a2);

    float hw1 = 0.5f * p2, hh1 = 0.5f * p3;
    float hw2 = 0.5f * t2, hh2 = 0.5f * t3;

    const float SX[4] = {0.5f, -0.5f, -0.5f, 0.5f};
    const float SY[4] = {0.5f, 0.5f, -0.5f, -0.5f};
    float P1x[4], P1y[4], P2x[4], P2y[4];
    #pragma unroll
    for (int k = 0; k < 4; ++k) {
        float xs = SX[k] * p2, ys = SY[k] * p3;
        P1x[k] = xs * c1_ - ys * s1 + p0;
        P1y[k] = xs * s1 + ys * c1_ + p1;
        float xs2 = SX[k] * t2, ys2 = SY[k] * t3;
        P2x[k] = xs2 * c2_ - ys2 * s2 + t0;
        P2y[k] = xs2 * s2 + ys2 * c2_ + t1;
    }

    float sum = 0.0f;
    #pragma unroll
    for (int k = 0; k < 4; ++k) {
        int kn = (k + 1) & 3;
        clip_edge_accum(P1x[k], P1y[k], P1x[kn]-P1x[k], P1y[kn]-P1y[k],
                        t0, t1, c2_, s2, hw2, hh2, sum);
    }
    #pragma unroll
    for (int k = 0; k < 4; ++k) {
        int kn = (k + 1) & 3;
        clip_edge_accum(P2x[k], P2y[k], P2x[kn]-P2x[k], P2y[kn]-P2y[k],
                        p0, p1, c1_, s1, hw1, hh1, sum);
    }

    float inter = 0.5f * fabsf(sum);
    float uni = p2 * p3 + t2 * t3 - inter;
    float iou = inter / (uni + FEPS);
    return fminf(fmaxf(iou, 1e-7f), 1.0f - 1e-7f);
}

// One box per thread; per-block partial STORED (not atomic) to its own slot.
// Every slot is written every launch -> no workspace init needed.
__global__ __launch_bounds__(256) void riou_kernel(
    const float* __restrict__ pred, const float* __restrict__ target,
    const int* __restrict__ pos_idx, float* __restrict__ out,
    float2* __restrict__ partials, int n)
{
    int gid = blockIdx.x * blockDim.x + threadIdx.x;
    float lnum = 0.0f, lden = 0.0f;

    if (gid < n) {
        const float* p = pred + (size_t)gid * 5;
        const float* t = target + (size_t)gid * 5;
        float iou = one_iou(p[0], p[1], p[2], p[3], p[4],
                            t[0], t[1], t[2], t[3], t[4]);
        out[1 + gid] = iou;
        float m = (pos_idx[gid] != 0) ? 1.0f : 0.0f;
        lnum = (1.0f - iou) * m;
        lden = m;
    }

    // block reduction (wave shuffle + cross-wave LDS)
    #pragma unroll
    for (int off = 32; off > 0; off >>= 1) {
        lnum += __shfl_down(lnum, off);
        lden += __shfl_down(lden, off);
    }
    __shared__ float snum[4], sden[4];
    int wave = threadIdx.x >> 6, lane = threadIdx.x & 63;
    if (lane == 0) { snum[wave] = lnum; sden[wave] = lden; }
    __syncthreads();
    if (threadIdx.x == 0) {
        float bn = snum[0] + snum[1] + snum[2] + snum[3];
        float bd = sden[0] + sden[1] + sden[2] + sden[3];
        partials[blockIdx.x] = make_float2(bn, bd);  // plain store, no atomic
    }
}

__global__ __launch_bounds__(256) void riou_finalize(
    const float2* __restrict__ partials, int nb, float* __restrict__ out)
{
    double num = 0.0, den = 0.0;
    for (int i = threadIdx.x; i < nb; i += 256) {
        float2 p = partials[i];
        num += (double)p.x;
        den += (double)p.y;
    }
    #pragma unroll
    for (int off = 32; off > 0; off >>= 1) {
        num += __shfl_down(num, off);
        den += __shfl_down(den, off);
    }
    __shared__ double dn[4], dd[4];
    int wave = threadIdx.x >> 6, lane = threadIdx.x & 63;
    if (lane == 0) { dn[wave] = num; dd[wave] = den; }
    __syncthreads();
    if (threadIdx.x == 0) {
        double n2 = dn[0] + dn[1] + dn[2] + dn[3];
        double d2 = dd[0] + dd[1] + dd[2] + dd[3];
        out[0] = (float)(n2 / fmax(d2, 1.0));
    }
}

extern "C" void kernel_launch(void* const* d_in, const int* in_sizes, int n_in,
                              void* d_out, int out_size, void* d_ws, size_t ws_size,
                              hipStream_t stream) {
    const float* pred   = (const float*)d_in[0];
    const float* target = (const float*)d_in[1];
    const int*   posidx = (const int*)d_in[2];
    float* out = (float*)d_out;

    int n = in_sizes[0] / 5;

    int block = 256;
    int grid = (n + block - 1) / block;
    float2* partials = (float2*)d_ws;

    riou_kernel<<<grid, block, 0, stream>>>(pred, target, posidx, out,
                                            partials, n);
    riou_finalize<<<1, block, 0, stream>>>(partials, grid, out);
}